// Round 3
// baseline (165.259 us; speedup 1.0000x reference)
//
#include <hip/hip_runtime.h>

// entmax-1.5 over rows of [R=16384, N=4096] fp32.
// tau* solves f(tau) = sum_i [z_i - tau]_+^2 = 1, z = (x - max)/2 (z_max = 0,
// tau* in [-1, 0)). Newton from tau = -1 is monotone from the left (f convex,
// decreasing). Structure per wave (one row):
//   1. max pass                                 (HBM read, 268 MB total)
//   2. two full-width Newton iterations         (reloads are L2-hot)
//   3. count + scan + compact survivors z>tau2 into LDS (value + column)
//   4. register Newton on <=256 survivors, break on |dtau| < 1e-7
//   5. zero-fill the output row (no x needed), s_waitcnt, scatter survivors
// Norm = s2 from the last Newton iteration (exact: non-survivors contribute 0).

#define ROWLEN 4096
#define CHUNKS 16   // float4 per lane
#define RPB 4       // rows (waves) per block
#define CAP 256     // survivor capacity per wave
#define SLOTS 4     // CAP / 64

__global__ __launch_bounds__(256) void entmax15_kernel(
    const float* __restrict__ x, float* __restrict__ out, int rows) {
    __shared__ float sv[RPB][CAP];  // survivor values (z - tau2)
    __shared__ int   si[RPB][CAP];  // survivor column indices
    const int wave = threadIdx.x >> 6;
    const int lane = threadIdx.x & 63;
    const int row = blockIdx.x * RPB + wave;
    if (row >= rows) return;  // wave-uniform

    const float* __restrict__ xr = x + (size_t)row * ROWLEN;
    float* __restrict__ orow = out + (size_t)row * ROWLEN;

    // ---- Pass 1: row max ----
    float m = -3.4e38f;
    #pragma unroll
    for (int k = 0; k < CHUNKS; ++k) {
        const float4 v = *reinterpret_cast<const float4*>(xr + (size_t)(k * 64 + lane) * 4);
        m = fmaxf(m, fmaxf(fmaxf(v.x, v.y), fmaxf(v.z, v.w)));
    }
    #pragma unroll
    for (int s = 1; s < 64; s <<= 1) m = fmaxf(m, __shfl_xor(m, s, 64));
    const float mh = m * 0.5f;  // z_i = fmaf(x_i, 0.5, -mh)

    // ---- Pass 2: two full-width Newton iterations from tau = -1 ----
    float tau = -1.0f;
    #pragma unroll
    for (int it = 0; it < 2; ++it) {
        const float c = -mh - tau;  // t = fmaf(x, 0.5, c) = z - tau
        float s1 = 0.0f, s2 = 0.0f;
        #pragma unroll
        for (int k = 0; k < CHUNKS; ++k) {
            const float4 v = *reinterpret_cast<const float4*>(xr + (size_t)(k * 64 + lane) * 4);
            float t;
            t = fmaxf(fmaf(v.x, 0.5f, c), 0.0f); s1 += t; s2 = fmaf(t, t, s2);
            t = fmaxf(fmaf(v.y, 0.5f, c), 0.0f); s1 += t; s2 = fmaf(t, t, s2);
            t = fmaxf(fmaf(v.z, 0.5f, c), 0.0f); s1 += t; s2 = fmaf(t, t, s2);
            t = fmaxf(fmaf(v.w, 0.5f, c), 0.0f); s1 += t; s2 = fmaf(t, t, s2);
        }
        #pragma unroll
        for (int s = 1; s < 64; s <<= 1) {
            s1 += __shfl_xor(s1, s, 64);
            s2 += __shfl_xor(s2, s, 64);
        }
        tau += (s2 - 1.0f) / fmaxf(2.0f * s1, 1e-20f);
    }
    const float c2 = -mh - tau;  // s_i = z_i - tau2; survivor iff s_i > 0

    // ---- Pass 3a: count survivors ----
    int cnt = 0;
    #pragma unroll
    for (int k = 0; k < CHUNKS; ++k) {
        const float4 v = *reinterpret_cast<const float4*>(xr + (size_t)(k * 64 + lane) * 4);
        cnt += (fmaf(v.x, 0.5f, c2) > 0.0f) ? 1 : 0;
        cnt += (fmaf(v.y, 0.5f, c2) > 0.0f) ? 1 : 0;
        cnt += (fmaf(v.z, 0.5f, c2) > 0.0f) ? 1 : 0;
        cnt += (fmaf(v.w, 0.5f, c2) > 0.0f) ? 1 : 0;
    }
    int pre = cnt;
    #pragma unroll
    for (int s = 1; s < 64; s <<= 1) {
        const int t = __shfl_up(pre, s, 64);
        if (lane >= s) pre += t;
    }
    const int K = __shfl(pre, 63, 64);  // wave-uniform total

    if (K <= CAP) {
        // ---- Pass 3b: compact (value, column) into wave-private LDS ----
        int idx = pre - cnt;
        #pragma unroll
        for (int k = 0; k < CHUNKS; ++k) {
            const float4 v = *reinterpret_cast<const float4*>(xr + (size_t)(k * 64 + lane) * 4);
            const int col0 = k * 256 + lane * 4;
            float s;
            s = fmaf(v.x, 0.5f, c2); if (s > 0.0f) { sv[wave][idx] = s; si[wave][idx] = col0 + 0; ++idx; }
            s = fmaf(v.y, 0.5f, c2); if (s > 0.0f) { sv[wave][idx] = s; si[wave][idx] = col0 + 1; ++idx; }
            s = fmaf(v.z, 0.5f, c2); if (s > 0.0f) { sv[wave][idx] = s; si[wave][idx] = col0 + 2; ++idx; }
            s = fmaf(v.w, 0.5f, c2); if (s > 0.0f) { sv[wave][idx] = s; si[wave][idx] = col0 + 3; ++idx; }
        }
        float r[SLOTS];
        #pragma unroll
        for (int j = 0; j < SLOTS; ++j) {
            const int q = lane + 64 * j;
            r[j] = (q < K) ? sv[wave][q] : -1.0f;  // pad: fmax(-1 - tp, 0) = 0 for tp >= 0
        }

        // ---- Pass 4: Newton on survivors, shifted variable tp = tau - tau2 >= 0 ----
        float tp = 0.0f, s2f = 1.0f;
        for (int it = 0; it < 12; ++it) {
            float s1 = 0.0f, s2 = 0.0f;
            #pragma unroll
            for (int j = 0; j < SLOTS; ++j) {
                const float t = fmaxf(r[j] - tp, 0.0f);
                s1 += t;
                s2 = fmaf(t, t, s2);
            }
            #pragma unroll
            for (int s = 1; s < 64; s <<= 1) {
                s1 += __shfl_xor(s1, s, 64);
                s2 += __shfl_xor(s2, s, 64);
            }
            const float dtau = (s2 - 1.0f) / fmaxf(2.0f * s1, 1e-20f);
            s2f = s2;
            tp += dtau;
            if (fabsf(dtau) < 1e-7f) break;  // wave-uniform (identical reduce tree)
        }
        const float inv = 1.0f / (s2f + 1e-8f);

        // ---- Pass 5: zero-fill row, then scatter survivors ----
        const float4 zz = make_float4(0.0f, 0.0f, 0.0f, 0.0f);
        #pragma unroll
        for (int k = 0; k < CHUNKS; ++k)
            *reinterpret_cast<float4*>(orow + (size_t)(k * 64 + lane) * 4) = zz;
        asm volatile("s_waitcnt vmcnt(0)" ::: "memory");  // zeros retire before scatter
        for (int q = lane; q < K; q += 64) {
            const float t = fmaxf(sv[wave][q] - tp, 0.0f);
            orow[si[wave][q]] = t * t * inv;
        }
    } else {
        // ---- Fallback (adversarial rows): full-width Newton + dense write ----
        float tp = tau, s2f = 1.0f;
        for (int it = 0; it < 20; ++it) {
            const float c = -mh - tp;
            float s1 = 0.0f, s2 = 0.0f;
            #pragma unroll
            for (int k = 0; k < CHUNKS; ++k) {
                const float4 v = *reinterpret_cast<const float4*>(xr + (size_t)(k * 64 + lane) * 4);
                float t;
                t = fmaxf(fmaf(v.x, 0.5f, c), 0.0f); s1 += t; s2 = fmaf(t, t, s2);
                t = fmaxf(fmaf(v.y, 0.5f, c), 0.0f); s1 += t; s2 = fmaf(t, t, s2);
                t = fmaxf(fmaf(v.z, 0.5f, c), 0.0f); s1 += t; s2 = fmaf(t, t, s2);
                t = fmaxf(fmaf(v.w, 0.5f, c), 0.0f); s1 += t; s2 = fmaf(t, t, s2);
            }
            #pragma unroll
            for (int s = 1; s < 64; s <<= 1) {
                s1 += __shfl_xor(s1, s, 64);
                s2 += __shfl_xor(s2, s, 64);
            }
            const float dtau = (s2 - 1.0f) / fmaxf(2.0f * s1, 1e-20f);
            s2f = s2;
            tp += dtau;
            if (fabsf(dtau) < 1e-7f) break;
        }
        const float inv = 1.0f / (s2f + 1e-8f);
        const float c = -mh - tp;
        #pragma unroll
        for (int k = 0; k < CHUNKS; ++k) {
            const float4 v = *reinterpret_cast<const float4*>(xr + (size_t)(k * 64 + lane) * 4);
            float4 o;
            float t;
            t = fmaxf(fmaf(v.x, 0.5f, c), 0.0f); o.x = t * t * inv;
            t = fmaxf(fmaf(v.y, 0.5f, c), 0.0f); o.y = t * t * inv;
            t = fmaxf(fmaf(v.z, 0.5f, c), 0.0f); o.z = t * t * inv;
            t = fmaxf(fmaf(v.w, 0.5f, c), 0.0f); o.w = t * t * inv;
            *reinterpret_cast<float4*>(orow + (size_t)(k * 64 + lane) * 4) = o;
        }
    }
}

extern "C" void kernel_launch(void* const* d_in, const int* in_sizes, int n_in,
                              void* d_out, int out_size, void* d_ws, size_t ws_size,
                              hipStream_t stream) {
    const float* x = (const float*)d_in[0];
    float* out = (float*)d_out;
    const int rows = in_sizes[0] / ROWLEN;  // 16384
    const int blocks = (rows + RPB - 1) / RPB;
    entmax15_kernel<<<blocks, 256, 0, stream>>>(x, out, rows);
}

// Round 4
// 75.344 us; speedup vs baseline: 2.1934x; 2.1934x over previous
//
#include <hip/hip_runtime.h>

// entmax-1.5 over rows of [R=16384, N=4096] fp32.
// tau* solves f(tau) = sum_i [z_i - tau]_+^2 = 1, z = (x - max)/2 (z_max = 0,
// tau* in [-1,0)). Newton from tau=-1 approaches the root monotonically from
// the left (f convex decreasing), converging quadratically.
// One wave per row, row register-resident (single HBM read):
//   1. load x -> z[64] regs; max via 6-step butterfly
//   2. two full-width Newton iterations (register passes, 1 fma + 1 fmax/elem)
//   3. count+scan survivors (x > xcut); compact values into wave-private LDS
//   4. Newton on <=4 survivor regs/lane, break on |dtau| < 1e-7 (~4 iters)
//   5. normalizer = last s2 (exact: non-survivors contribute 0)
//   6. dense nontemporal float4 write from regs (write-once data: bypass L2/L3
//      so the 256 MiB input stays L3-resident across replays)

#define ROWLEN 4096
#define ELEMS 64
#define CHUNKS 16
#define RPB 4
#define CAP 256
#define SLOTS 4

typedef float f4 __attribute__((ext_vector_type(4)));

__global__ __launch_bounds__(256) void entmax15_kernel(
    const float* __restrict__ x, float* __restrict__ out, int rows) {
    __shared__ float sv[RPB][CAP];  // wave-private survivor values, no barriers
    const int wave = threadIdx.x >> 6;
    const int lane = threadIdx.x & 63;
    const int row = blockIdx.x * RPB + wave;
    if (row >= rows) return;  // wave-uniform

    const float* __restrict__ xr = x + (size_t)row * ROWLEN;
    float* __restrict__ orow = out + (size_t)row * ROWLEN;

    // ---- Load row into registers (only HBM read of x) ----
    float z[ELEMS];
    #pragma unroll
    for (int k = 0; k < CHUNKS; ++k) {
        const float4 v = *reinterpret_cast<const float4*>(xr + (size_t)(k * 64 + lane) * 4);
        z[4 * k + 0] = v.x;
        z[4 * k + 1] = v.y;
        z[4 * k + 2] = v.z;
        z[4 * k + 3] = v.w;
    }

    // ---- Row max ----
    float m = z[0];
    #pragma unroll
    for (int i = 1; i < ELEMS; ++i) m = fmaxf(m, z[i]);
    #pragma unroll
    for (int s = 1; s < 64; s <<= 1) m = fmaxf(m, __shfl_xor(m, s, 64));
    const float mh = m * 0.5f;  // z_i - tau = fmaf(x_i, 0.5, -mh - tau)

    // ---- Two full-width Newton iterations from tau = -1 ----
    float tau = -1.0f;
    #pragma unroll
    for (int it = 0; it < 2; ++it) {
        const float c = -mh - tau;
        float s1 = 0.0f, s2 = 0.0f;
        #pragma unroll
        for (int i = 0; i < ELEMS; ++i) {
            const float t = fmaxf(fmaf(z[i], 0.5f, c), 0.0f);
            s1 += t;
            s2 = fmaf(t, t, s2);
        }
        #pragma unroll
        for (int s = 1; s < 64; s <<= 1) {
            s1 += __shfl_xor(s1, s, 64);
            s2 += __shfl_xor(s2, s, 64);
        }
        tau += (s2 - 1.0f) / fmaxf(2.0f * s1, 1e-20f);
    }
    const float c2 = -mh - tau;
    const float xcut = -2.0f * c2;  // survivor iff x > xcut  (<=> z - tau2 > 0)

    // ---- Count + exclusive scan ----
    int cnt = 0;
    #pragma unroll
    for (int i = 0; i < ELEMS; ++i) cnt += (z[i] > xcut) ? 1 : 0;
    int pre = cnt;
    #pragma unroll
    for (int s = 1; s < 64; s <<= 1) {
        const int t = __shfl_up(pre, s, 64);
        if (lane >= s) pre += t;
    }
    const int K = __shfl(pre, 63, 64);  // wave-uniform (>=1: max element survives)

    float tauF, inv;
    if (K <= CAP) {
        // ---- Compact survivor values (order irrelevant) into LDS ----
        int idx = pre - cnt;
        #pragma unroll
        for (int i = 0; i < ELEMS; ++i) {
            if (z[i] > xcut) { sv[wave][idx] = fmaf(z[i], 0.5f, c2); ++idx; }
        }
        float r[SLOTS];
        #pragma unroll
        for (int j = 0; j < SLOTS; ++j) {
            const int q = lane + 64 * j;
            r[j] = (q < K) ? sv[wave][q] : -1.0f;  // pad contributes 0 for tp >= 0
        }
        // ---- Newton on survivors, tp = tau - tau2 >= 0 ----
        float tp = 0.0f, s2f = 1.0f;
        for (int it = 0; it < 10; ++it) {
            float s1 = 0.0f, s2 = 0.0f;
            #pragma unroll
            for (int j = 0; j < SLOTS; ++j) {
                const float t = fmaxf(r[j] - tp, 0.0f);
                s1 += t;
                s2 = fmaf(t, t, s2);
            }
            #pragma unroll
            for (int s = 1; s < 64; s <<= 1) {
                s1 += __shfl_xor(s1, s, 64);
                s2 += __shfl_xor(s2, s, 64);
            }
            const float dtau = (s2 - 1.0f) / fmaxf(2.0f * s1, 1e-20f);
            s2f = s2;
            tp += dtau;
            if (fabsf(dtau) < 1e-7f) break;  // wave-uniform (identical reduce tree)
        }
        tauF = tau + tp;
        inv = 1.0f / (s2f + 1e-8f);
    } else {
        // ---- Fallback (adversarial rows): continue full-width from regs ----
        float s2f = 1.0f;
        for (int it = 0; it < 20; ++it) {
            const float c = -mh - tau;
            float s1 = 0.0f, s2 = 0.0f;
            #pragma unroll
            for (int i = 0; i < ELEMS; ++i) {
                const float t = fmaxf(fmaf(z[i], 0.5f, c), 0.0f);
                s1 += t;
                s2 = fmaf(t, t, s2);
            }
            #pragma unroll
            for (int s = 1; s < 64; s <<= 1) {
                s1 += __shfl_xor(s1, s, 64);
                s2 += __shfl_xor(s2, s, 64);
            }
            const float dtau = (s2 - 1.0f) / fmaxf(2.0f * s1, 1e-20f);
            s2f = s2;
            tau += dtau;
            if (fabsf(dtau) < 1e-7f) break;
        }
        tauF = tau;
        inv = 1.0f / (s2f + 1e-8f);
    }

    // ---- Dense output from registers, nontemporal (write-once) ----
    const float cF = -mh - tauF;
    #pragma unroll
    for (int k = 0; k < CHUNKS; ++k) {
        f4 o;
        float t;
        t = fmaxf(fmaf(z[4 * k + 0], 0.5f, cF), 0.0f); o.x = t * t * inv;
        t = fmaxf(fmaf(z[4 * k + 1], 0.5f, cF), 0.0f); o.y = t * t * inv;
        t = fmaxf(fmaf(z[4 * k + 2], 0.5f, cF), 0.0f); o.z = t * t * inv;
        t = fmaxf(fmaf(z[4 * k + 3], 0.5f, cF), 0.0f); o.w = t * t * inv;
        __builtin_nontemporal_store(o, reinterpret_cast<f4*>(orow + (size_t)(k * 64 + lane) * 4));
    }
}

extern "C" void kernel_launch(void* const* d_in, const int* in_sizes, int n_in,
                              void* d_out, int out_size, void* d_ws, size_t ws_size,
                              hipStream_t stream) {
    const float* x = (const float*)d_in[0];
    float* out = (float*)d_out;
    const int rows = in_sizes[0] / ROWLEN;  // 16384
    const int blocks = (rows + RPB - 1) / RPB;
    entmax15_kernel<<<blocks, 256, 0, stream>>>(x, out, rows);
}